// Round 6
// baseline (42.984 us; speedup 1.0000x reference)
//
#include <hip/hip_runtime.h>
#include <math.h>

#define B 8
#define H 384
#define W 384
#define HW (H*W)
#define NTOT (B*HW)
#define INF_I 10000
#define NFB 192            // fused-reduction blocks in stage1
#define NVB 48             // vertical-EDT blocks in stage1
#define NRB 768            // row blocks (4 rows each)
#define NGRP 48            // completion groups (16 row-blocks each)

// ws layout (bytes):
//   gcount @ 0       : NGRP uint (row-block completion counters)
//   part2  @ 512     : NFB*25 doubles (38400 B)  fused partials
//   part   @ 38912   : NRB doubles (6144 B)      row partials
//   g2u    @ 63488   : NTOT uint      (dpos | dneg<<16)
//   sumA   @ 4782080 : HW float       (sum_b |p - t|)

// ---------------- launch 1: fused BCE/dice/sumA + vertical EDT ----------------
__global__ __launch_bounds__(768) void k_stage1(const float* __restrict__ pred,
                                                const int* __restrict__ tgt,
                                                float* __restrict__ sumA,
                                                double* __restrict__ part2,
                                                unsigned* __restrict__ g2u,
                                                unsigned* __restrict__ gcount) {
    __shared__ float lds[12][25];
    __shared__ unsigned bmsh[12][64];
    int tid = threadIdx.x;

    if (blockIdx.x < NFB) {
        if (blockIdx.x == 0 && tid < NGRP) gcount[tid] = 0u;   // reset for this call
        // ---- fused BCE + dice partials + sumA: one pixel/thread, 8 batches ----
        int pix = blockIdx.x * 768 + tid;
        float vals[25];                    // 0=bce, 1+b=p, 9+b=p*t, 17+b=t
        float sA = 0.f, bce = 0.f;
#pragma unroll
        for (int b = 0; b < 8; ++b) {
            float x = pred[b * HW + pix];
            int t = tgt[b * HW + pix];
            float e = expf(-fabsf(x));
            float r = 1.f / (1.f + e);
            float p = (x >= 0.f) ? r : 1.f - r;                // stable sigmoid
            bce += fmaxf(x, 0.f) + log1pf(e) - x * (float)t;   // softplus - x*t
            vals[1 + b] = p;
            vals[9 + b] = t ? p : 0.f;
            vals[17 + b] = (float)t;
            sA += t ? 1.f - p : p;
        }
        sumA[pix] = sA;
        vals[0] = bce;
#pragma unroll
        for (int k = 0; k < 25; ++k)
#pragma unroll
            for (int o = 32; o; o >>= 1) vals[k] += __shfl_down(vals[k], o);
        int wave = tid >> 6, lane = tid & 63;
        if (lane == 0)
#pragma unroll
            for (int k = 0; k < 25; ++k) lds[wave][k] = vals[k];
        __syncthreads();
        if (tid < 25) {
            double s = 0.0;
#pragma unroll
            for (int wv = 0; wv < 12; ++wv) s += (double)lds[wv][tid];
            part2[blockIdx.x * 25 + tid] = s;
        }
    } else {
        // ---- vertical distance, word-parallel: thread = (32-row word, column) ----
        int vb = blockIdx.x - NFB;
        int wd = tid >> 6;                 // 0..11
        int wl = tid & 63;
        int b = vb / 6;
        int w = (vb % 6) * 64 + wl;

        const int* colp = tgt + b * HW + w + (wd * 32) * W;
        unsigned m = 0;
#pragma unroll
        for (int i = 0; i < 32; ++i)
            m |= (colp[i * W] != 0) ? (1u << i) : 0u;
        bmsh[wd][wl] = m;
        __syncthreads();

        unsigned mp = m, mn = ~m;
        int dfe_p = INF_I, dfe_n = INF_I, dbe_p = INF_I, dbe_n = INF_I;
        if (wd > 0) {
            int k = wd - 1; unsigned mm;
            while ((mm = bmsh[k][wl]) == 0 && k > 0) --k;
            if (mm) dfe_p = wd * 32 - 1 - (k * 32 + 31 - __clz(mm));
            k = wd - 1;
            while ((mm = ~bmsh[k][wl]) == 0 && k > 0) --k;
            if (mm) dfe_n = wd * 32 - 1 - (k * 32 + 31 - __clz(mm));
        }
        if (wd < 11) {
            int k = wd + 1; unsigned mm;
            while ((mm = bmsh[k][wl]) == 0 && k < 11) ++k;
            if (mm) dbe_p = k * 32 + (__ffs(mm) - 1) - (wd + 1) * 32;
            k = wd + 1;
            while ((mm = ~bmsh[k][wl]) == 0 && k < 11) ++k;
            if (mm) dbe_n = k * 32 + (__ffs(mm) - 1) - (wd + 1) * 32;
        }

        int dfp[32], dfn[32];
        int cp = dfe_p, cn = dfe_n;
#pragma unroll
        for (int i = 0; i < 32; ++i) {
            cp = ((mp >> i) & 1u) ? 0 : min(cp + 1, INF_I);
            cn = ((mn >> i) & 1u) ? 0 : min(cn + 1, INF_I);
            dfp[i] = cp; dfn[i] = cn;
        }
        unsigned* outc = g2u + b * HW + (wd * 32) * W + w;
        cp = dbe_p; cn = dbe_n;
#pragma unroll
        for (int i = 31; i >= 0; --i) {
            cp = ((mp >> i) & 1u) ? 0 : min(cp + 1, INF_I);
            cn = ((mn >> i) & 1u) ? 0 : min(cn + 1, INF_I);
            int dp = min(dfp[i], cp);
            int dn = min(dfn[i], cn);
            outc[i * W] = (unsigned)dp | ((unsigned)dn << 16);
        }
    }
}

// ---------------- launch 2: row envelope + loss2 dot + final combine ----------------
// blocks 0..NRB-1: 4 rows each. block NRB: combiner (spin on group counters).
__global__ __launch_bounds__(64) void k_row2(const unsigned* __restrict__ g2u,
                                             const float* __restrict__ sumA,
                                             double* __restrict__ part,
                                             const double* __restrict__ part2,
                                             unsigned* __restrict__ gcount,
                                             float* __restrict__ out) {
    int tid = threadIdx.x;

    if (blockIdx.x == NRB) {
        // ---- combiner: loss1 sums first (overlaps with row blocks running) ----
        __shared__ double sval[25];
        double sv = 0.0;
        if (tid < 25) {
#pragma unroll 4
            for (int blk = 0; blk < NFB; ++blk) sv += part2[blk * 25 + tid];
            sval[tid] = sv;
        }
        // ---- spin until all 48 groups report 16 done (atomics: coherent) ----
        if (tid == 0) {
            for (int g = 0; g < NGRP; ++g) {
                while (atomicAdd(&gcount[g], 0u) < 16u) __builtin_amdgcn_s_sleep(8);
            }
        }
        __syncthreads();
        // ---- coherent read of row partials, fixed-order deterministic sum ----
        double s2 = 0.0;
        for (int i = tid; i < NRB; i += 64)
            s2 += __longlong_as_double(
                atomicAdd((unsigned long long*)&part[i], 0ull));
#pragma unroll
        for (int o = 32; o; o >>= 1) s2 += __shfl_down(s2, o);
        if (tid == 0) {
            double bce = sval[0] / (double)NTOT;
            double dsum = 0.0;
            for (int bb = 0; bb < 8; ++bb)
                dsum += (2.0 * sval[9 + bb] + 1e-5) / (sval[1 + bb] + sval[17 + bb] + 1e-5);
            double dice = dsum / 8.0;
            double loss1 = 0.5 * bce + (1.0 - dice);
            double loss2 = s2 / ((double)B * (double)B * (double)HW);
            out[0] = (float)(0.7 * loss1 + 0.03 * loss2);
        }
        return;
    }

    // ---- row blocks: 4 consecutive rows ----
    __shared__ float lfp[W + W/16 + 2], lfn[W + W/16 + 2];   // +1 pad per 16
    const float DD[17] = {64.f,49.f,36.f,25.f,16.f,9.f,4.f,1.f,0.f,
                          1.f,4.f,9.f,16.f,25.f,36.f,49.f,64.f};
    double vsum = 0.0;
#pragma unroll 1
    for (int rr = 0; rr < 4; ++rr) {
        int bh = blockIdx.x * 4 + rr;
        int b = bh / H, h = bh % H;
        const unsigned* row = g2u + b * HW + h * W;
        __syncthreads();
        for (int q = tid; q < W; q += 64) {
            unsigned v = row[q];
            float dp = (float)(v & 0xFFFFu);
            float dn = (float)(v >> 16);
            int s = q + (q >> 4);
            lfp[s] = dp * dp;             // exact: ints <= 1e4 -> d^2 <= 1e8
            lfn[s] = dn * dn;
        }
        __syncthreads();

        int base = 6 * tid - 8;
        float rp[22], rn[22];
#pragma unroll
        for (int r = 0; r < 22; ++r) {
            int j = base + r;
            j = j < 0 ? 0 : (j > W - 1 ? W - 1 : j);
            int s = j + (j >> 4);
            rp[r] = lfp[s];
            rn[r] = lfn[s];
        }
        float partial = 0.f;
#pragma unroll
        for (int q = 0; q < 6; ++q) {
            int i = 6 * tid + q;
            float Dp = 3.0e38f, Dn = 3.0e38f;
#pragma unroll
            for (int tt = 0; tt < 17; ++tt) {
                Dp = fminf(Dp, rp[q + tt] + DD[tt]);
                Dn = fminf(Dn, rn[q + tt] + DD[tt]);
            }
            if (Dp > 64.f || Dn > 64.f) {     // exactness not proven -> full row
                float fi = (float)i;
                for (int j = 0; j < W; ++j) {
                    int s = j + (j >> 4);
                    float d = fi - (float)j;
                    Dp = fminf(Dp, fmaf(d, d, lfp[s]));
                    Dn = fminf(Dn, fmaf(d, d, lfn[s]));
                }
            }
            float sdf = fabsf(sqrtf(Dp) - sqrtf(Dn));
            partial += sdf * sumA[h * W + i];
        }
        vsum += (double)partial;
    }
#pragma unroll
    for (int o = 32; o; o >>= 1) vsum += __shfl_down(vsum, o);
    if (tid == 0) {
        // publish partial (coherent), order with bare vmcnt wait (NO wbl2 fence),
        // then signal the group counter. R4 lesson: never __threadfence here.
        atomicExch((unsigned long long*)&part[blockIdx.x], __double_as_longlong(vsum));
        asm volatile("s_waitcnt vmcnt(0)" ::: "memory");
        atomicAdd(&gcount[blockIdx.x >> 4], 1u);
    }
}

extern "C" void kernel_launch(void* const* d_in, const int* in_sizes, int n_in,
                              void* d_out, int out_size, void* d_ws, size_t ws_size,
                              hipStream_t stream) {
    const float* pred = (const float*)d_in[0];
    const int* tgt = (const int*)d_in[1];
    float* out = (float*)d_out;
    char* ws = (char*)d_ws;
    unsigned* gcount = (unsigned*)ws;
    double* part2 = (double*)(ws + 512);
    double* part = (double*)(ws + 38912);
    unsigned* g2u = (unsigned*)(ws + 63488);
    float* sumA = (float*)(ws + 4782080);

    k_stage1<<<NFB + NVB, 768, 0, stream>>>(pred, tgt, sumA, part2, g2u, gcount);
    k_row2<<<NRB + 1, 64, 0, stream>>>(g2u, sumA, part, part2, gcount, out);
}

// Round 7
// 36.928 us; speedup vs baseline: 1.1640x; 1.1640x over previous
//
#include <hip/hip_runtime.h>
#include <math.h>

#define B 8
#define H 384
#define W 384
#define HW (H*W)
#define NTOT (B*HW)
#define INF_I 10000
#define NFB 192            // fused-reduction blocks in stage1
#define NVB 48             // vertical-EDT blocks in stage1
#define NRB 256            // row blocks (12 rows = 12 waves each)
#define NGRP 8             // accumulator groups (32 row-blocks each)

// ws layout (bytes):
//   sync   @ 0       : NGRP*256 B  (acc double @ g*256, cnt uint @ g*256+128)
//   part2  @ 4096    : NFB*25 doubles (38400 B)  fused partials
//   g2u    @ 63488   : NTOT uint   (dpos | dneg<<16)
//   sumA   @ 4782080 : HW float    (sum_b |p - t|)

// ---------------- launch 1: fused BCE/dice/sumA + vertical EDT ----------------
__global__ __launch_bounds__(768) void k_stage1(const float* __restrict__ pred,
                                                const int* __restrict__ tgt,
                                                float* __restrict__ sumA,
                                                double* __restrict__ part2,
                                                unsigned* __restrict__ g2u,
                                                char* __restrict__ syncws) {
    __shared__ float lds[12][25];
    __shared__ unsigned bmsh[12][64];
    int tid = threadIdx.x;

    if (blockIdx.x < NFB) {
        // ---- fused BCE + dice partials + sumA: one pixel/thread, 8 batches ----
        int pix = blockIdx.x * 768 + tid;
        float vals[25];                    // 0=bce, 1+b=p, 9+b=p*t, 17+b=t
        float sA = 0.f, bce = 0.f;
#pragma unroll
        for (int b = 0; b < 8; ++b) {
            float x = pred[b * HW + pix];
            int t = tgt[b * HW + pix];
            float e = expf(-fabsf(x));
            float r = 1.f / (1.f + e);
            float p = (x >= 0.f) ? r : 1.f - r;                // stable sigmoid
            bce += fmaxf(x, 0.f) + log1pf(e) - x * (float)t;   // softplus - x*t
            vals[1 + b] = p;
            vals[9 + b] = t ? p : 0.f;
            vals[17 + b] = (float)t;
            sA += t ? 1.f - p : p;
        }
        sumA[pix] = sA;
        vals[0] = bce;
#pragma unroll
        for (int k = 0; k < 25; ++k)
#pragma unroll
            for (int o = 32; o; o >>= 1) vals[k] += __shfl_down(vals[k], o);
        int wave = tid >> 6, lane = tid & 63;
        if (lane == 0)
#pragma unroll
            for (int k = 0; k < 25; ++k) lds[wave][k] = vals[k];
        __syncthreads();
        if (tid < 25) {
            double s = 0.0;
#pragma unroll
            for (int wv = 0; wv < 12; ++wv) s += (double)lds[wv][tid];
            part2[blockIdx.x * 25 + tid] = s;
        }
    } else {
        // vert block 0 resets the sync accumulators/counters for this call
        if (blockIdx.x == NFB && tid < 16) {
            if (tid < 8) *(double*)(syncws + tid * 256) = 0.0;
            else         *(unsigned*)(syncws + (tid - 8) * 256 + 128) = 0u;
        }
        // ---- vertical distance, word-parallel: thread = (32-row word, column) ----
        int vb = blockIdx.x - NFB;
        int wd = tid >> 6;                 // 0..11
        int wl = tid & 63;
        int b = vb / 6;
        int w = (vb % 6) * 64 + wl;

        const int* colp = tgt + b * HW + w + (wd * 32) * W;
        unsigned m = 0;
#pragma unroll
        for (int i = 0; i < 32; ++i)
            m |= (colp[i * W] != 0) ? (1u << i) : 0u;
        bmsh[wd][wl] = m;
        __syncthreads();

        unsigned mp = m, mn = ~m;
        int dfe_p = INF_I, dfe_n = INF_I, dbe_p = INF_I, dbe_n = INF_I;
        if (wd > 0) {
            int k = wd - 1; unsigned mm;
            while ((mm = bmsh[k][wl]) == 0 && k > 0) --k;
            if (mm) dfe_p = wd * 32 - 1 - (k * 32 + 31 - __clz(mm));
            k = wd - 1;
            while ((mm = ~bmsh[k][wl]) == 0 && k > 0) --k;
            if (mm) dfe_n = wd * 32 - 1 - (k * 32 + 31 - __clz(mm));
        }
        if (wd < 11) {
            int k = wd + 1; unsigned mm;
            while ((mm = bmsh[k][wl]) == 0 && k < 11) ++k;
            if (mm) dbe_p = k * 32 + (__ffs(mm) - 1) - (wd + 1) * 32;
            k = wd + 1;
            while ((mm = ~bmsh[k][wl]) == 0 && k < 11) ++k;
            if (mm) dbe_n = k * 32 + (__ffs(mm) - 1) - (wd + 1) * 32;
        }

        int dfp[32], dfn[32];
        int cp = dfe_p, cn = dfe_n;
#pragma unroll
        for (int i = 0; i < 32; ++i) {
            cp = ((mp >> i) & 1u) ? 0 : min(cp + 1, INF_I);
            cn = ((mn >> i) & 1u) ? 0 : min(cn + 1, INF_I);
            dfp[i] = cp; dfn[i] = cn;
        }
        unsigned* outc = g2u + b * HW + (wd * 32) * W + w;
        cp = dbe_p; cn = dbe_n;
#pragma unroll
        for (int i = 31; i >= 0; --i) {
            cp = ((mp >> i) & 1u) ? 0 : min(cp + 1, INF_I);
            cn = ((mn >> i) & 1u) ? 0 : min(cn + 1, INF_I);
            int dp = min(dfp[i], cp);
            int dn = min(dfn[i], cn);
            outc[i * W] = (unsigned)dp | ((unsigned)dn << 16);
        }
    }
}

// ---------------- launch 2: row envelope (12 rows/block) + tree tail + final ----------------
__global__ __launch_bounds__(768) void k_rows(const unsigned* __restrict__ g2u,
                                              const float* __restrict__ sumA,
                                              const double* __restrict__ part2,
                                              char* __restrict__ syncws,
                                              float* __restrict__ out) {
    int tid = threadIdx.x;
    int wv = tid >> 6, lane = tid & 63;
    __shared__ float lfp[12][W + W/16 + 2], lfn[12][W + W/16 + 2];
    __shared__ double wpart[12];
    __shared__ double sval[25];

    // ---- one row per wave ----
    int bh = blockIdx.x * 12 + wv;
    int b = bh / H, h = bh % H;
    const unsigned* row = g2u + b * HW + h * W;
    for (int q = lane; q < W; q += 64) {
        unsigned v = row[q];
        float dp = (float)(v & 0xFFFFu);
        float dn = (float)(v >> 16);
        int s = q + (q >> 4);
        lfp[wv][s] = dp * dp;             // exact: ints <= 1e4 -> d^2 <= 1e8
        lfn[wv][s] = dn * dn;
    }
    __syncthreads();

    int base = 6 * lane - 8;
    float rp[22], rn[22];
#pragma unroll
    for (int r = 0; r < 22; ++r) {
        int j = base + r;
        j = j < 0 ? 0 : (j > W - 1 ? W - 1 : j);
        int s = j + (j >> 4);
        rp[r] = lfp[wv][s];
        rn[r] = lfn[wv][s];
    }
    const float DD[17] = {64.f,49.f,36.f,25.f,16.f,9.f,4.f,1.f,0.f,
                          1.f,4.f,9.f,16.f,25.f,36.f,49.f,64.f};
    float partial = 0.f;
#pragma unroll
    for (int q = 0; q < 6; ++q) {
        int i = 6 * lane + q;
        float Dp = 3.0e38f, Dn = 3.0e38f;
#pragma unroll
        for (int tt = 0; tt < 17; ++tt) {
            Dp = fminf(Dp, rp[q + tt] + DD[tt]);
            Dn = fminf(Dn, rn[q + tt] + DD[tt]);
        }
        if (Dp > 64.f || Dn > 64.f) {     // exactness not proven -> full row
            float fi = (float)i;
            for (int j = 0; j < W; ++j) {
                int s = j + (j >> 4);
                float d = fi - (float)j;
                Dp = fminf(Dp, fmaf(d, d, lfp[wv][s]));
                Dn = fminf(Dn, fmaf(d, d, lfn[wv][s]));
            }
        }
        float sdf = fabsf(sqrtf(Dp) - sqrtf(Dn));
        partial += sdf * sumA[h * W + i];
    }
    double v = partial;
#pragma unroll
    for (int o = 32; o; o >>= 1) v += __shfl_down(v, o);
    if (lane == 0) wpart[wv] = v;
    __syncthreads();

    if (tid == 0) {
        double bp = 0.0;
#pragma unroll
        for (int k = 0; k < 12; ++k) bp += wpart[k];
        int g = blockIdx.x & (NGRP - 1);
        atomicAdd((double*)(syncws + g * 256), bp);
        asm volatile("s_waitcnt vmcnt(0)" ::: "memory");   // order acc before cnt (no fence)
        atomicAdd((unsigned*)(syncws + g * 256 + 128), 1u);
    }

    // ---- block 0: overlapped loss1 reduction, then poll 8 counters, combine ----
    if (blockIdx.x == 0) {
        if (tid < 200) {
            int vv = tid >> 3, sub = tid & 7;
            double s = 0.0;
            for (int blk = sub; blk < NFB; blk += 8) s += part2[blk * 25 + vv];
#pragma unroll
            for (int o = 4; o; o >>= 1) s += __shfl_down(s, o);
            if (sub == 0) sval[vv] = s;
        }
        __syncthreads();
        if (tid == 0) {
            for (int g = 0; g < NGRP; ++g)
                while (atomicAdd((unsigned*)(syncws + g * 256 + 128), 0u) < 32u)
                    __builtin_amdgcn_s_sleep(2);
            double s2 = 0.0;
            for (int g = 0; g < NGRP; ++g)               // fixed order
                s2 += atomicAdd((double*)(syncws + g * 256), 0.0);
            double bce = sval[0] / (double)NTOT;
            double dsum = 0.0;
            for (int bb = 0; bb < 8; ++bb)
                dsum += (2.0 * sval[9 + bb] + 1e-5) / (sval[1 + bb] + sval[17 + bb] + 1e-5);
            double dice = dsum / 8.0;
            double loss1 = 0.5 * bce + (1.0 - dice);
            double loss2 = s2 / ((double)B * (double)B * (double)HW);
            out[0] = (float)(0.7 * loss1 + 0.03 * loss2);
        }
    }
}

extern "C" void kernel_launch(void* const* d_in, const int* in_sizes, int n_in,
                              void* d_out, int out_size, void* d_ws, size_t ws_size,
                              hipStream_t stream) {
    const float* pred = (const float*)d_in[0];
    const int* tgt = (const int*)d_in[1];
    float* out = (float*)d_out;
    char* ws = (char*)d_ws;
    char* syncws = ws;
    double* part2 = (double*)(ws + 4096);
    unsigned* g2u = (unsigned*)(ws + 63488);
    float* sumA = (float*)(ws + 4782080);

    k_stage1<<<NFB + NVB, 768, 0, stream>>>(pred, tgt, sumA, part2, g2u, syncws);
    k_rows<<<NRB, 768, 0, stream>>>(g2u, sumA, part2, syncws, out);
}